// Round 11
// baseline (2386.680 us; speedup 1.0000x reference)
//
#include <hip/hip_runtime.h>

#define N_NODES 100000
#define N_EDGES 1600000
#define NGRAPHS 256
#define BN_EPS 1e-5f
#define NBUK ((N_NODES + 511) >> 9)           // 196 buckets of 512 dst nodes
#define BCAP 8704                             // padded bucket capacity (mean 8163)
#define BIN_EPB 2048                          // edges per binning block
#define BIN_BLOCKS ((N_EDGES + BIN_EPB - 1) / BIN_EPB)  // 782
#define NRANGE 16                             // src>>13 -> 0..12 used
#define PBLK (NBUK * 4)                       // 784 pull blocks of 128 nodes

// ---- helpers ----------------------------------------------------------------

__device__ __forceinline__ unsigned f2ord(float f) {
  unsigned u = __float_as_uint(f);
  return (u & 0x80000000u) ? ~u : (u | 0x80000000u);
}

__device__ __forceinline__ float ord2f(unsigned u) {
  unsigned bits = (u & 0x80000000u) ? (u ^ 0x80000000u) : ~u;
  return __uint_as_float(bits);
}

__device__ __forceinline__ unsigned short f2bf(float f) {   // RNE f32 -> bf16
  unsigned u = __float_as_uint(f);
  unsigned r = u + 0x7FFFu + ((u >> 16) & 1u);
  return (unsigned short)(r >> 16);
}

__device__ __forceinline__ float bf2f(unsigned short b) {
  return __uint_as_float(((unsigned)b) << 16);
}

// Detect int64 vs int32 edge_index + init bucket cursors + zero pooled.
__global__ void detect_init(const unsigned* __restrict__ ei, int* __restrict__ flag,
                            int* __restrict__ cursor, unsigned* __restrict__ pooled) {
  const int tid = threadIdx.x;
  if (tid < NBUK) cursor[tid] = tid * BCAP;
  for (int i = tid; i < NGRAPHS * 64; i += 256) pooled[i] = 0u;  // ordered -inf
  if (tid == 0) {
    int f = 1;
    for (int i = 1; i < 64; i += 2) {
      if (ei[i] != 0u) { f = 0; break; }
    }
    *flag = f;
  }
}

__global__ void detect_i64(const unsigned* __restrict__ ei, int* __restrict__ flag) {
  if (blockIdx.x == 0 && threadIdx.x == 0) {
    int f = 1;
    for (int i = 1; i < 64; i += 2) {
      if (ei[i] != 0u) { f = 0; break; }
    }
    *flag = f;
  }
}

__device__ __forceinline__ int load_idx(const void* p, const int* flag, long long i) {
  return (*flag) ? (int)((const long long*)p)[i] : ((const int*)p)[i];
}

// ---- CSR build: bin edges by dst>>9 into padded bucket slots ----------------
// tmp record: x = src | (localdst9 << 18), y = weight bits.

__global__ __launch_bounds__(256) void binpass(const void* __restrict__ eiPtr,
                                               const int* __restrict__ flag,
                                               const float* __restrict__ ew,
                                               int* __restrict__ cursor,
                                               int2* __restrict__ tmp) {
  __shared__ int cnt[NBUK];
  __shared__ int base[NBUK];
  const int tid = threadIdx.x;
  const long long chunk0 = (long long)blockIdx.x * BIN_EPB;
  for (int i = tid; i < NBUK; i += 256) cnt[i] = 0;
  __syncthreads();
  int pk[8], wb[8], rk[8], bk[8];
  const bool i64 = (*flag != 0);
  #pragma unroll
  for (int j = 0; j < 8; ++j) {
    long long e = chunk0 + j * 256 + tid;
    rk[j] = -1;
    if (e < N_EDGES) {
      int s, d;
      if (i64) {
        const long long* ei = (const long long*)eiPtr;
        s = (int)ei[e]; d = (int)ei[N_EDGES + e];
      } else {
        const int* ei = (const int*)eiPtr;
        s = ei[e]; d = ei[N_EDGES + e];
      }
      wb[j] = __float_as_int(ew[e]);
      bk[j] = d >> 9;
      pk[j] = s | ((d & 511) << 18);
      rk[j] = atomicAdd(&cnt[bk[j]], 1);
    }
  }
  __syncthreads();
  for (int b = tid; b < NBUK; b += 256) {
    int c = cnt[b];
    base[b] = c ? atomicAdd(&cursor[b], c) : 0;
  }
  __syncthreads();
  #pragma unroll
  for (int j = 0; j < 8; ++j) {
    if (rk[j] >= 0) {
      int pos = base[bk[j]] + rk[j];
      if (pos < (bk[j] + 1) * BCAP) {        // overflow guard (statistically never)
        int2 r; r.x = pk[j]; r.y = wb[j];
        tmp[pos] = r;
      }
    }
  }
}

// One block per 512-bucket: sort its slice by key = (sub128, srcRange) into
// csrR; emit rangeBase[(b*4+sub)*17 + r] boundaries. Payload: src | ln7<<17.
__global__ __launch_bounds__(256) void place3(const int2* __restrict__ tmp,
                                              const int* __restrict__ cursor,
                                              int* __restrict__ rangeBase,
                                              int2* __restrict__ csrR) {
  __shared__ int cnt[64];
  __shared__ int cur[64];
  const int b = blockIdx.x;
  const int tid = threadIdx.x;
  const int beg = b * BCAP;
  int cntb = cursor[b] - beg;
  if (cntb > BCAP) cntb = BCAP;
  const int end = beg + cntb;
  if (tid < 64) cnt[tid] = 0;
  __syncthreads();
  for (int i = beg + tid; i < end; i += 256) {
    int pk = tmp[i].x;
    int key = (((pk >> 25) & 3) << 4) | ((pk & 0x3FFFF) >> 13);
    atomicAdd(&cnt[key], 1);
  }
  __syncthreads();
  if (tid == 0) {                             // serial 64-entry exclusive scan
    int run = beg;
    #pragma unroll
    for (int k = 0; k < 64; ++k) { int c = cnt[k]; cnt[k] = run; run += c; }
  }
  __syncthreads();
  if (tid < 64) {
    cur[tid] = cnt[tid];
    int sub = tid >> 4, r = tid & 15;
    rangeBase[(b * 4 + sub) * 17 + r] = cnt[tid];
    if (r == 15) rangeBase[(b * 4 + sub) * 17 + 16] = (tid < 63) ? cnt[tid + 1] : end;
  }
  __syncthreads();
  for (int i = beg + tid; i < end; i += 256) {
    int2 e = tmp[i];
    int pk = e.x;
    int key = (((pk >> 25) & 3) << 4) | ((pk & 0x3FFFF) >> 13);
    int pos = atomicAdd(&cur[key], 1);
    int2 r; r.x = (pk & 0x1FFFF) | (((pk >> 18) & 127) << 17); r.y = e.y;
    csrR[pos] = r;
  }
}

// ---- GEMM: u[N][64](bf16) = A[N][64] @ W  (no bias / no relu) ---------------

template<bool F32IN>
__global__ __launch_bounds__(256) void gemm_u(const void* __restrict__ Ain,
                                              const float* __restrict__ W,
                                              unsigned short* __restrict__ Uout,
                                              int N) {
  __shared__ float Wt[64][68];   // Wt[c][k]
  __shared__ float At[64][68];
  const int tid = threadIdx.x;
  const int rowBase = blockIdx.x * 64;

  for (int i = tid; i < 4096; i += 256) {
    int k = i >> 6, c = i & 63;
    Wt[c][k] = W[i];
  }
  if (F32IN) {
    const float4* A4 = (const float4*)Ain;
    #pragma unroll
    for (int j = 0; j < 4; ++j) {
      int t4 = tid + j * 256;
      int g4 = rowBase * 16 + t4;
      float4 v = make_float4(0.f, 0.f, 0.f, 0.f);
      if (g4 < N * 16) v = A4[g4];
      int r = t4 >> 4, k4 = t4 & 15;
      *(float4*)&At[r][k4 * 4] = v;
    }
  } else {
    const uint4* A16 = (const uint4*)Ain;
    #pragma unroll
    for (int j = 0; j < 2; ++j) {
      int q = tid + j * 256;
      int r = q >> 3, c8 = (q & 7) * 8;
      int grow = rowBase + r;
      uint4 v = make_uint4(0u, 0u, 0u, 0u);
      if (grow < N) v = A16[(size_t)grow * 8 + (q & 7)];
      float4 f0, f1;
      f0.x = bf2f((unsigned short)(v.x & 0xFFFFu)); f0.y = bf2f((unsigned short)(v.x >> 16));
      f0.z = bf2f((unsigned short)(v.y & 0xFFFFu)); f0.w = bf2f((unsigned short)(v.y >> 16));
      f1.x = bf2f((unsigned short)(v.z & 0xFFFFu)); f1.y = bf2f((unsigned short)(v.z >> 16));
      f1.z = bf2f((unsigned short)(v.w & 0xFFFFu)); f1.w = bf2f((unsigned short)(v.w >> 16));
      *(float4*)&At[r][c8] = f0;
      *(float4*)&At[r][c8 + 4] = f1;
    }
  }
  __syncthreads();

  const int c = tid & 63;
  const int r0 = (tid >> 6) * 16;
  float acc[16];
  #pragma unroll
  for (int i = 0; i < 16; ++i) acc[i] = 0.f;

  for (int k0 = 0; k0 < 64; k0 += 4) {
    float4 w = *(const float4*)&Wt[c][k0];
    #pragma unroll
    for (int i = 0; i < 16; ++i) {
      float4 a = *(const float4*)&At[r0 + i][k0];
      acc[i] += a.x * w.x + a.y * w.y + a.z * w.z + a.w * w.w;
    }
  }

  #pragma unroll
  for (int i = 0; i < 16; ++i) {
    int row = rowBase + r0 + i;
    if (row < N) Uout[(size_t)row * 64 + c] = f2bf(acc[i]);
  }
}

// ---- pull3: 128-node block, LDS fp32 acc, source-range-phased gathers -------
// All 784 blocks co-resident (32KB LDS): each range phase touches a 1MB table
// slice chip-wide -> gathers hit XCD L2. ds_add_f32 sink, no rowPtr needed.

template<bool POOL>
__global__ __launch_bounds__(256) void pull3(const unsigned short* __restrict__ T,
                                             const int2* __restrict__ csrR,
                                             const int* __restrict__ rangeBase,
                                             const float* __restrict__ bias,
                                             const void* __restrict__ bPtr,
                                             const int* __restrict__ flag,
                                             unsigned short* __restrict__ Hout,
                                             unsigned* __restrict__ pooled) {
  __shared__ float acc[128][64];             // 32 KB
  const int blk = blockIdx.x;
  const int tid = threadIdx.x;
  const int lane = tid & 63;
  const int w = __builtin_amdgcn_readfirstlane(tid >> 6);
  float* accF = &acc[0][0];
  for (int i = tid; i < 128 * 64; i += 256) accF[i] = 0.f;
  __syncthreads();

  const int* rb = rangeBase + blk * 17;
  for (int r = 0; r < NRANGE; ++r) {
    const int beg = rb[r], end = rb[r + 1];
    const int cnt = end - beg;
    const int chunk = (cnt + 3) >> 2;
    int i0 = beg + w * chunk;
    const int i1 = min(i0 + chunk, end);
    while (i0 < i1) {                        // clamped 8-deep pipelined gathers
      const int last = i1 - 1;
      int2 m[8]; float wt[8];
      #pragma unroll
      for (int j = 0; j < 8; ++j) {
        int idx = i0 + j;
        int c = idx < last ? idx : last;
        m[j] = csrR[c];
        wt[j] = (idx < i1) ? __int_as_float(m[j].y) : 0.f;
      }
      float v[8];
      #pragma unroll
      for (int j = 0; j < 8; ++j)
        v[j] = bf2f(T[(size_t)(m[j].x & 0x1FFFF) * 64 + lane]);
      #pragma unroll
      for (int j = 0; j < 8; ++j) {
        int ln = (m[j].x >> 17) & 127;
        atomicAdd(&acc[ln][lane], wt[j] * v[j]);
      }
      i0 += 8;
    }
    __syncthreads();                         // keep blocks phase-aligned
  }

  const float bl = bias[lane];
  const int nodeBase = blk * 128;
  if (!POOL) {
    for (int ln = w * 32; ln < w * 32 + 32; ++ln) {
      int n = nodeBase + ln;
      if (n < N_NODES)
        Hout[(size_t)n * 64 + lane] = f2bf(fmaxf(acc[ln][lane] + bl, 0.f));
    }
  } else {
    int curg = -1; float best = -3.4e38f;
    for (int ln = w * 32; ln < w * 32 + 32; ++ln) {
      int n = nodeBase + ln;
      if (n >= N_NODES) break;
      int g = load_idx(bPtr, flag, n);
      float v = acc[ln][lane] + bl;
      if (g != curg) {
        if (curg >= 0) atomicMax(&pooled[curg * 64 + lane], f2ord(best));
        curg = g; best = v;
      } else {
        best = fmaxf(best, v);
      }
    }
    if (curg >= 0) atomicMax(&pooled[curg * 64 + lane], f2ord(best));
  }
}

// ---- fallback path (small ws): dense GEMM + atomic scatter ------------------

template<bool RELU_IN, bool ADD_BIAS, bool RELU_OUT>
__global__ __launch_bounds__(256) void gemm64(const float* A,
                                              const float* __restrict__ W,
                                              const float* __restrict__ b,
                                              float* C, int N) {
  __shared__ float Wt[64][68];
  __shared__ float At[64][68];
  const int tid = threadIdx.x;
  const int rowBase = blockIdx.x * 64;

  for (int i = tid; i < 4096; i += 256) {
    int k = i >> 6, c = i & 63;
    Wt[c][k] = W[i];
  }
  const float4* A4 = (const float4*)A;
  #pragma unroll
  for (int j = 0; j < 4; ++j) {
    int t4 = tid + j * 256;
    int g4 = rowBase * 16 + t4;
    float4 v = make_float4(0.f, 0.f, 0.f, 0.f);
    if (g4 < N * 16) v = A4[g4];
    if (RELU_IN) {
      v.x = fmaxf(v.x, 0.f); v.y = fmaxf(v.y, 0.f);
      v.z = fmaxf(v.z, 0.f); v.w = fmaxf(v.w, 0.f);
    }
    int r = t4 >> 4, k4 = t4 & 15;
    *(float4*)&At[r][k4 * 4] = v;
  }
  __syncthreads();

  const int c = tid & 63;
  const int r0 = (tid >> 6) * 16;
  float acc[16];
  #pragma unroll
  for (int i = 0; i < 16; ++i) acc[i] = 0.f;

  for (int k0 = 0; k0 < 64; k0 += 4) {
    float4 w = *(const float4*)&Wt[c][k0];
    #pragma unroll
    for (int i = 0; i < 16; ++i) {
      float4 a = *(const float4*)&At[r0 + i][k0];
      acc[i] += a.x * w.x + a.y * w.y + a.z * w.z + a.w * w.w;
    }
  }

  const float bias = ADD_BIAS ? b[c] : 0.f;
  #pragma unroll
  for (int i = 0; i < 16; ++i) {
    int row = rowBase + r0 + i;
    if (row < N) {
      float v = acc[i] + bias;
      if (RELU_OUT) v = fmaxf(v, 0.f);
      C[row * 64 + c] = v;
    }
  }
}

__global__ __launch_bounds__(256) void init_bias(float* __restrict__ agg,
                                                 const float* __restrict__ b, int n4) {
  int i = blockIdx.x * 256 + threadIdx.x;
  if (i >= n4) return;
  ((float4*)agg)[i] = ((const float4*)b)[i & 15];
}

__global__ __launch_bounds__(256) void scatter_add(const float* __restrict__ h,
                                                   const void* __restrict__ eiPtr,
                                                   const int* __restrict__ flag,
                                                   const float* __restrict__ ew,
                                                   float* __restrict__ agg) {
  int gtid = blockIdx.x * 256 + threadIdx.x;
  int e = gtid >> 6, lane = gtid & 63;
  if (e >= N_EDGES) return;
  int s = load_idx(eiPtr, flag, e);
  int d = load_idx(eiPtr, flag, (long long)N_EDGES + e);
  atomicAdd(&agg[d * 64 + lane], ew[e] * h[s * 64 + lane]);
}

__global__ __launch_bounds__(256) void seg_max(const float* __restrict__ h,
                                               const void* __restrict__ bPtr,
                                               const int* __restrict__ flag,
                                               unsigned* __restrict__ pooled) {
  int gtid = blockIdx.x * 256 + threadIdx.x;
  int n = gtid >> 6, lane = gtid & 63;
  if (n >= N_NODES) return;
  int g = load_idx(bPtr, flag, n);
  atomicMax(&pooled[g * 64 + lane], f2ord(h[n * 64 + lane]));
}

// ---- BatchNorm + linear head ------------------------------------------------

__global__ __launch_bounds__(256) void bn_head(const unsigned* __restrict__ pooled,
                                               const float* __restrict__ gamma,
                                               const float* __restrict__ beta,
                                               const float* __restrict__ linW,
                                               const float* __restrict__ linb,
                                               float* __restrict__ out) {
  __shared__ float P[NGRAPHS][64 + 1];
  __shared__ float mean_s[64], rstd_s[64];
  const int tid = threadIdx.x;

  for (int i = tid; i < NGRAPHS * 64; i += 256) {
    P[i >> 6][i & 63] = ord2f(pooled[i]);
  }
  __syncthreads();

  if (tid < 64) {
    float s = 0.f, ss = 0.f;
    for (int g = 0; g < NGRAPHS; ++g) {
      float v = P[g][tid];
      s += v; ss += v * v;
    }
    float m = s / (float)NGRAPHS;
    float var = ss / (float)NGRAPHS - m * m;
    mean_s[tid] = m;
    rstd_s[tid] = rsqrtf(var + BN_EPS);
  }
  __syncthreads();

  float acc = linb[0];
  #pragma unroll 8
  for (int c = 0; c < 64; ++c) {
    float normed = (P[tid][c] - mean_s[c]) * rstd_s[c] * gamma[c] + beta[c];
    acc += normed * linW[c];
  }
  out[tid] = acc;
}

// ---- launch -----------------------------------------------------------------

extern "C" void kernel_launch(void* const* d_in, const int* in_sizes, int n_in,
                              void* d_out, int out_size, void* d_ws, size_t ws_size,
                              hipStream_t stream) {
  const float* x     = (const float*)d_in[0];
  const void*  ei    = d_in[1];
  const float* ew    = (const float*)d_in[2];
  const void*  batch = d_in[3];
  const float* W1    = (const float*)d_in[4];
  const float* b1    = (const float*)d_in[5];
  const float* W2    = (const float*)d_in[6];
  const float* b2    = (const float*)d_in[7];
  const float* W3    = (const float*)d_in[8];
  const float* b3    = (const float*)d_in[9];
  const float* gamma = (const float*)d_in[10];
  const float* beta  = (const float*)d_in[11];
  const float* linW  = (const float*)d_in[12];
  const float* linb  = (const float*)d_in[13];

  char* ws = (char*)d_ws;
  const size_t MAT  = (size_t)N_NODES * 64 * sizeof(float);           // 25.6 MB
  const size_t TBL  = (size_t)N_NODES * 64 * sizeof(unsigned short);  // 12.8 MB
  const size_t CSRP = (size_t)NBUK * BCAP * sizeof(int2);             // 13.65 MB
  const size_t RNGB = ((size_t)PBLK * 17 * sizeof(int) + 255) & ~(size_t)255;

  size_t off = 0;
  unsigned short* uA = (unsigned short*)(ws + off); off += TBL;  // tmpP aliases uA+hB
  unsigned short* hB = (unsigned short*)(ws + off); off += TBL;
  int2*  csrR   = (int2*)(ws + off);           off += CSRP;
  int*   rangeBase = (int*)(ws + off);         off += RNGB;
  int*   cursor = (int*)(ws + off);            off += 1024;
  unsigned* pooled = (unsigned*)(ws + off);    off += (size_t)NGRAPHS * 64 * sizeof(unsigned);
  int*   flag   = (int*)(ws + off);            off += 256;
  const bool csrPath = (ws_size >= off);

  const int gemmBlocks = (N_NODES + 63) / 64;             // 1563
  const int nodeWaveBlocks = (N_NODES * 64) / 256;        // 25000

  if (csrPath) {
    int2* tmpP = (int2*)uA;   // 13.65 MB: spans uA + head of hB; dead before gemm1
    // ---- build CSR (padded buckets; per-128-block src-range-sorted lists) ----
    detect_init<<<1, 256, 0, stream>>>((const unsigned*)ei, flag, cursor, pooled);
    binpass<<<BIN_BLOCKS, 256, 0, stream>>>(ei, flag, ew, cursor, tmpP);
    place3<<<NBUK, 256, 0, stream>>>(tmpP, cursor, rangeBase, csrR);

    // ---- reference-order layers: u = h@W (gemm), then aggregate+bias(+relu) ----
    gemm_u<true><<<gemmBlocks, 256, 0, stream>>>(x, W1, uA, N_NODES);
    pull3<false><<<PBLK, 256, 0, stream>>>(uA, csrR, rangeBase, b1, batch, flag, hB, nullptr);
    gemm_u<false><<<gemmBlocks, 256, 0, stream>>>(hB, W2, uA, N_NODES);
    pull3<false><<<PBLK, 256, 0, stream>>>(uA, csrR, rangeBase, b2, batch, flag, hB, nullptr);
    gemm_u<false><<<gemmBlocks, 256, 0, stream>>>(hB, W3, uA, N_NODES);
    pull3<true><<<PBLK, 256, 0, stream>>>(uA, csrR, rangeBase, b3, batch, flag, nullptr, pooled);

    bn_head<<<1, 256, 0, stream>>>(pooled, gamma, beta, linW, linb, (float*)d_out);
  } else {
    // ---- fallback: atomic scatter path ----
    float* h   = (float*)ws;
    float* agg = (float*)(ws + MAT);
    unsigned* pooled2 = (unsigned*)(ws + 2 * MAT);
    int* flag2 = (int*)(ws + 2 * MAT + (size_t)NGRAPHS * 64 * sizeof(unsigned));
    detect_i64<<<1, 64, 0, stream>>>((const unsigned*)ei, flag2);
    const int n4 = N_NODES * 16;
    const int initBlocks = (n4 + 255) / 256;
    const int scatBlocks = (N_EDGES * 64) / 256;

    gemm64<false, false, false><<<gemmBlocks, 256, 0, stream>>>(x, W1, b1, h, N_NODES);
    init_bias<<<initBlocks, 256, 0, stream>>>(agg, b1, n4);
    scatter_add<<<scatBlocks, 256, 0, stream>>>(h, ei, flag2, ew, agg);
    gemm64<true, false, false><<<gemmBlocks, 256, 0, stream>>>(agg, W2, b2, h, N_NODES);
    init_bias<<<initBlocks, 256, 0, stream>>>(agg, b2, n4);
    scatter_add<<<scatBlocks, 256, 0, stream>>>(h, ei, flag2, ew, agg);
    gemm64<true, false, false><<<gemmBlocks, 256, 0, stream>>>(agg, W3, b3, h, N_NODES);
    init_bias<<<initBlocks, 256, 0, stream>>>(agg, b3, n4);
    scatter_add<<<scatBlocks, 256, 0, stream>>>(h, ei, flag2, ew, agg);

    hipMemsetAsync(pooled2, 0, (size_t)NGRAPHS * 64 * sizeof(unsigned), stream);
    seg_max<<<nodeWaveBlocks, 256, 0, stream>>>(agg, batch, flag2, pooled2);
    bn_head<<<1, 256, 0, stream>>>(pooled2, gamma, beta, linW, linb, (float*)d_out);
  }
}

// Round 12
// 290.421 us; speedup vs baseline: 8.2180x; 8.2180x over previous
//
#include <hip/hip_runtime.h>

#define N_NODES 100000
#define N_EDGES 1600000
#define NGRAPHS 256
#define BN_EPS 1e-5f
#define NBUK ((N_NODES + 511) >> 9)           // 196 buckets of 512 dst nodes
#define BCAP 8704                             // padded bucket capacity (mean 8163)
#define BIN_EPB 2048                          // edges per binning block
#define BIN_BLOCKS ((N_EDGES + BIN_EPB - 1) / BIN_EPB)  // 782
#define POOL_RUN 8

// ---- helpers ----------------------------------------------------------------

__device__ __forceinline__ unsigned f2ord(float f) {
  unsigned u = __float_as_uint(f);
  return (u & 0x80000000u) ? ~u : (u | 0x80000000u);
}

__device__ __forceinline__ float ord2f(unsigned u) {
  unsigned bits = (u & 0x80000000u) ? (u ^ 0x80000000u) : ~u;
  return __uint_as_float(bits);
}

__device__ __forceinline__ unsigned short f2bf(float f) {   // RNE f32 -> bf16
  unsigned u = __float_as_uint(f);
  unsigned r = u + 0x7FFFu + ((u >> 16) & 1u);
  return (unsigned short)(r >> 16);
}

__device__ __forceinline__ float bf2f(unsigned short b) {
  return __uint_as_float(((unsigned)b) << 16);
}

// Detect int64 vs int32 edge_index + init bucket cursors + zero pooled.
__global__ void detect_init(const unsigned* __restrict__ ei, int* __restrict__ flag,
                            int* __restrict__ cursor, unsigned* __restrict__ pooled) {
  const int tid = threadIdx.x;
  if (tid < NBUK) cursor[tid] = tid * BCAP;
  for (int i = tid; i < NGRAPHS * 64; i += 256) pooled[i] = 0u;  // ordered -inf
  if (tid == 0) {
    int f = 1;
    for (int i = 1; i < 64; i += 2) {
      if (ei[i] != 0u) { f = 0; break; }
    }
    *flag = f;
  }
}

__global__ void detect_i64(const unsigned* __restrict__ ei, int* __restrict__ flag) {
  if (blockIdx.x == 0 && threadIdx.x == 0) {
    int f = 1;
    for (int i = 1; i < 64; i += 2) {
      if (ei[i] != 0u) { f = 0; break; }
    }
    *flag = f;
  }
}

__device__ __forceinline__ int load_idx(const void* p, const int* flag, long long i) {
  return (*flag) ? (int)((const long long*)p)[i] : ((const int*)p)[i];
}

// ---- CSR build: bin edges by dst>>9 into padded bucket slots ----------------
// tmp record: x = src | (localdst<<18), y = weight bits.

__global__ __launch_bounds__(256) void binpass(const void* __restrict__ eiPtr,
                                               const int* __restrict__ flag,
                                               const float* __restrict__ ew,
                                               int* __restrict__ cursor,
                                               int2* __restrict__ tmp) {
  __shared__ int cnt[NBUK];
  __shared__ int base[NBUK];
  const int tid = threadIdx.x;
  const long long chunk0 = (long long)blockIdx.x * BIN_EPB;
  for (int i = tid; i < NBUK; i += 256) cnt[i] = 0;
  __syncthreads();
  int pk[8], wb[8], rk[8], bk[8];
  const bool i64 = (*flag != 0);
  #pragma unroll
  for (int j = 0; j < 8; ++j) {
    long long e = chunk0 + j * 256 + tid;
    rk[j] = -1;
    if (e < N_EDGES) {
      int s, d;
      if (i64) {
        const long long* ei = (const long long*)eiPtr;
        s = (int)ei[e]; d = (int)ei[N_EDGES + e];
      } else {
        const int* ei = (const int*)eiPtr;
        s = ei[e]; d = ei[N_EDGES + e];
      }
      wb[j] = __float_as_int(ew[e]);
      bk[j] = d >> 9;
      pk[j] = s | ((d & 511) << 18);
      rk[j] = atomicAdd(&cnt[bk[j]], 1);
    }
  }
  __syncthreads();
  for (int b = tid; b < NBUK; b += 256) {
    int c = cnt[b];
    base[b] = c ? atomicAdd(&cursor[b], c) : 0;
  }
  __syncthreads();
  #pragma unroll
  for (int j = 0; j < 8; ++j) {
    if (rk[j] >= 0) {
      int pos = base[bk[j]] + rk[j];
      if (pos < (bk[j] + 1) * BCAP) {        // overflow guard (statistically never)
        int2 r; r.x = pk[j]; r.y = wb[j];
        tmp[pos] = r;
      }
    }
  }
}

// ---- merged kernel: blocks [0,NBUK) do place2; rest do layer-1 GEMM ---------
// place2: local hist(512)+LDS scan -> rowPtr2{beg,end}, scatter bucket slice
// into node-sorted csrP (L2-hot window). gemm: uA = x @ W1 (bf16 out).
// Independent workloads -> overlap in one dispatch.

__global__ __launch_bounds__(256) void place2_gemm1(
    const int2* __restrict__ tmp, const int* __restrict__ cursor,
    int2* __restrict__ rowPtr2, int2* __restrict__ csrP,
    const float* __restrict__ x, const float* __restrict__ W,
    unsigned short* __restrict__ Uout) {
  __shared__ float smem[2][64][68];          // 34.8 KB, unioned
  const int tid = threadIdx.x;

  if (blockIdx.x < NBUK) {
    int* cnt = (int*)&smem[0][0][0];
    int* sc  = cnt + 512;
    int* cur = sc + 256;
    const int b = blockIdx.x;
    const int beg = b * BCAP;
    int cntb = cursor[b] - beg;
    if (cntb > BCAP) cntb = BCAP;
    const int end = beg + cntb;
    cnt[tid] = 0; cnt[tid + 256] = 0;
    __syncthreads();
    for (int i = beg + tid; i < end; i += 256) {
      atomicAdd(&cnt[(tmp[i].x >> 18) & 511], 1);
    }
    __syncthreads();
    int c0 = cnt[2 * tid], c1 = cnt[2 * tid + 1];
    int pairSum = c0 + c1;
    sc[tid] = pairSum;
    __syncthreads();
    for (int off = 1; off < 256; off <<= 1) {
      int t = (tid >= off) ? sc[tid - off] : 0;
      __syncthreads();
      sc[tid] += t;
      __syncthreads();
    }
    int exclPair = sc[tid] - pairSum;
    int base0 = beg + exclPair;
    int base1 = base0 + c0;
    int g0 = (b << 9) + 2 * tid;
    if (g0 < N_NODES)     { int2 r; r.x = base0; r.y = base0 + c0; rowPtr2[g0] = r; }
    if (g0 + 1 < N_NODES) { int2 r; r.x = base1; r.y = base1 + c1; rowPtr2[g0 + 1] = r; }
    cur[2 * tid] = base0;
    cur[2 * tid + 1] = base1;
    __syncthreads();
    for (int i = beg + tid; i < end; i += 256) {
      int2 e = tmp[i];
      int pos = atomicAdd(&cur[(e.x >> 18) & 511], 1);
      int2 r; r.x = e.x & 0x3FFFF; r.y = e.y;
      csrP[pos] = r;
    }
  } else {
    const int rowBase = (blockIdx.x - NBUK) * 64;
    float (*Wt)[68] = (float(*)[68])&smem[0][0][0];   // Wt[c][k]
    float (*At)[68] = (float(*)[68])&smem[1][0][0];
    for (int i = tid; i < 4096; i += 256) {
      int k = i >> 6, c = i & 63;
      Wt[c][k] = W[i];
    }
    const float4* A4 = (const float4*)x;
    #pragma unroll
    for (int j = 0; j < 4; ++j) {
      int t4 = tid + j * 256;
      int g4 = rowBase * 16 + t4;
      float4 v = make_float4(0.f, 0.f, 0.f, 0.f);
      if (g4 < N_NODES * 16) v = A4[g4];
      int r = t4 >> 4, k4 = t4 & 15;
      *(float4*)&At[r][k4 * 4] = v;
    }
    __syncthreads();

    const int c = tid & 63;
    const int r0 = (tid >> 6) * 16;
    float acc[16];
    #pragma unroll
    for (int i = 0; i < 16; ++i) acc[i] = 0.f;
    for (int k0 = 0; k0 < 64; k0 += 4) {
      float4 w = *(const float4*)&Wt[c][k0];
      #pragma unroll
      for (int i = 0; i < 16; ++i) {
        float4 a = *(const float4*)&At[r0 + i][k0];
        acc[i] += a.x * w.x + a.y * w.y + a.z * w.z + a.w * w.w;
      }
    }
    #pragma unroll
    for (int i = 0; i < 16; ++i) {
      int row = rowBase + r0 + i;
      if (row < N_NODES) Uout[(size_t)row * 64 + c] = f2bf(acc[i]);
    }
  }
}

// ---- GEMM: u[N][64](bf16) = A[N][64](bf16) @ W  (layers 2,3) ----------------

__global__ __launch_bounds__(256) void gemm_u(const unsigned short* __restrict__ Ain,
                                              const float* __restrict__ W,
                                              unsigned short* __restrict__ Uout,
                                              int N) {
  __shared__ float Wt[64][68];   // Wt[c][k]
  __shared__ float At[64][68];
  const int tid = threadIdx.x;
  const int rowBase = blockIdx.x * 64;

  for (int i = tid; i < 4096; i += 256) {
    int k = i >> 6, c = i & 63;
    Wt[c][k] = W[i];
  }
  const uint4* A16 = (const uint4*)Ain;
  #pragma unroll
  for (int j = 0; j < 2; ++j) {
    int q = tid + j * 256;
    int r = q >> 3, c8 = (q & 7) * 8;
    int grow = rowBase + r;
    uint4 v = make_uint4(0u, 0u, 0u, 0u);
    if (grow < N) v = A16[(size_t)grow * 8 + (q & 7)];
    float4 f0, f1;
    f0.x = bf2f((unsigned short)(v.x & 0xFFFFu)); f0.y = bf2f((unsigned short)(v.x >> 16));
    f0.z = bf2f((unsigned short)(v.y & 0xFFFFu)); f0.w = bf2f((unsigned short)(v.y >> 16));
    f1.x = bf2f((unsigned short)(v.z & 0xFFFFu)); f1.y = bf2f((unsigned short)(v.z >> 16));
    f1.z = bf2f((unsigned short)(v.w & 0xFFFFu)); f1.w = bf2f((unsigned short)(v.w >> 16));
    *(float4*)&At[r][c8] = f0;
    *(float4*)&At[r][c8 + 4] = f1;
  }
  __syncthreads();

  const int c = tid & 63;
  const int r0 = (tid >> 6) * 16;
  float acc[16];
  #pragma unroll
  for (int i = 0; i < 16; ++i) acc[i] = 0.f;

  for (int k0 = 0; k0 < 64; k0 += 4) {
    float4 w = *(const float4*)&Wt[c][k0];
    #pragma unroll
    for (int i = 0; i < 16; ++i) {
      float4 a = *(const float4*)&At[r0 + i][k0];
      acc[i] += a.x * w.x + a.y * w.y + a.z * w.z + a.w * w.w;
    }
  }

  #pragma unroll
  for (int i = 0; i < 16; ++i) {
    int row = rowBase + r0 + i;
    if (row < N) Uout[(size_t)row * 64 + c] = f2bf(acc[i]);
  }
}

// ---- software-pipelined scalar-meta gather ----------------------------------
// Wave = one node, lane = feature. Meta wave-uniform (s_load); gathers 128B/wave.
// Ping-pong batches: while FMA-consuming batch A, batch B's 8 gathers stay in
// flight (s_waitcnt before FMA(A) only drains A).

struct GBatch { int2 m[8]; float w[8]; float v[8]; };

__device__ __forceinline__ void gload(GBatch& B, const int2* __restrict__ csr,
                                      int i, int end,
                                      const unsigned short* __restrict__ T, int lane) {
  const int last = end - 1;
  #pragma unroll
  for (int j = 0; j < 8; ++j) {
    int idx = i + j;
    int c = idx < last ? idx : last;          // scalar clamp
    B.m[j] = csr[c];
    B.w[j] = (idx < end) ? __int_as_float(B.m[j].y) : 0.f;
  }
  #pragma unroll
  for (int j = 0; j < 8; ++j)
    B.v[j] = bf2f(T[(size_t)B.m[j].x * 64 + lane]);
}

__device__ __forceinline__ void gfma(const GBatch& B, float& a0, float& a1,
                                     float& a2, float& a3) {
  a0 = fmaf(B.w[0], B.v[0], a0);
  a1 = fmaf(B.w[1], B.v[1], a1);
  a2 = fmaf(B.w[2], B.v[2], a2);
  a3 = fmaf(B.w[3], B.v[3], a3);
  a0 = fmaf(B.w[4], B.v[4], a0);
  a1 = fmaf(B.w[5], B.v[5], a1);
  a2 = fmaf(B.w[6], B.v[6], a2);
  a3 = fmaf(B.w[7], B.v[7], a3);
}

__device__ __forceinline__ float gather_pipe(const unsigned short* __restrict__ T,
                                             const int2* __restrict__ csr,
                                             int beg, int end, int lane) {
  const int cnt = end - beg;
  if (cnt <= 0) return 0.f;
  float a0 = 0.f, a1 = 0.f, a2 = 0.f, a3 = 0.f;
  GBatch A, B;
  const int nb = (cnt + 7) >> 3;
  gload(A, csr, beg, end, T, lane);
  int b = 1;
  while (b + 1 < nb) {
    gload(B, csr, beg + 8 * b, end, T, lane);
    gfma(A, a0, a1, a2, a3);
    gload(A, csr, beg + 8 * (b + 1), end, T, lane);
    gfma(B, a0, a1, a2, a3);
    b += 2;
  }
  if (b < nb) {
    gload(B, csr, beg + 8 * b, end, T, lane);
    gfma(A, a0, a1, a2, a3);
    gfma(B, a0, a1, a2, a3);
  } else {
    gfma(A, a0, a1, a2, a3);
  }
  return (a0 + a1) + (a2 + a3);
}

// ---- pull + bias + relu -> bf16 table ---------------------------------------

__global__ __launch_bounds__(256) void pull_relu(const unsigned short* __restrict__ T,
                                                 const int2* __restrict__ rowPtr2,
                                                 const int2* __restrict__ csr,
                                                 const float* __restrict__ bias,
                                                 unsigned short* __restrict__ Hout) {
  int wid = __builtin_amdgcn_readfirstlane((blockIdx.x * 256 + threadIdx.x) >> 6);
  const int lane = threadIdx.x & 63;
  if (wid >= N_NODES) return;
  const int2 be = rowPtr2[wid];
  float acc = gather_pipe(T, csr, be.x, be.y, lane);
  Hout[(size_t)wid * 64 + lane] = f2bf(fmaxf(acc + bias[lane], 0.f));
}

// ---- pull + bias + run-length segment-max pooling (layer 3) -----------------

__global__ __launch_bounds__(256) void pull_pool(const unsigned short* __restrict__ T,
                                                 const int2* __restrict__ rowPtr2,
                                                 const int2* __restrict__ csr,
                                                 const float* __restrict__ bias,
                                                 const void* __restrict__ bPtr,
                                                 const int* __restrict__ flag,
                                                 unsigned* __restrict__ pooled) {
  int wseq = __builtin_amdgcn_readfirstlane((blockIdx.x * 256 + threadIdx.x) >> 6);
  const int lane = threadIdx.x & 63;
  const int n0 = wseq * POOL_RUN;
  if (n0 >= N_NODES) return;
  const int n1 = min(n0 + POOL_RUN, N_NODES);
  const float blane = bias[lane];
  int curg = load_idx(bPtr, flag, n0);
  float best = -3.4e38f;
  for (int n = n0; n < n1; ++n) {
    const int2 be = rowPtr2[n];
    float acc = gather_pipe(T, csr, be.x, be.y, lane);
    float v = acc + blane;
    int g = load_idx(bPtr, flag, n);
    if (g != curg) {
      atomicMax(&pooled[curg * 64 + lane], f2ord(best));
      curg = g; best = v;
    } else {
      best = fmaxf(best, v);
    }
  }
  atomicMax(&pooled[curg * 64 + lane], f2ord(best));
}

// ---- fallback path (small ws): dense GEMM + atomic scatter ------------------

template<bool RELU_IN, bool ADD_BIAS, bool RELU_OUT>
__global__ __launch_bounds__(256) void gemm64(const float* A,
                                              const float* __restrict__ W,
                                              const float* __restrict__ b,
                                              float* C, int N) {
  __shared__ float Wt[64][68];
  __shared__ float At[64][68];
  const int tid = threadIdx.x;
  const int rowBase = blockIdx.x * 64;

  for (int i = tid; i < 4096; i += 256) {
    int k = i >> 6, c = i & 63;
    Wt[c][k] = W[i];
  }
  const float4* A4 = (const float4*)A;
  #pragma unroll
  for (int j = 0; j < 4; ++j) {
    int t4 = tid + j * 256;
    int g4 = rowBase * 16 + t4;
    float4 v = make_float4(0.f, 0.f, 0.f, 0.f);
    if (g4 < N * 16) v = A4[g4];
    if (RELU_IN) {
      v.x = fmaxf(v.x, 0.f); v.y = fmaxf(v.y, 0.f);
      v.z = fmaxf(v.z, 0.f); v.w = fmaxf(v.w, 0.f);
    }
    int r = t4 >> 4, k4 = t4 & 15;
    *(float4*)&At[r][k4 * 4] = v;
  }
  __syncthreads();

  const int c = tid & 63;
  const int r0 = (tid >> 6) * 16;
  float acc[16];
  #pragma unroll
  for (int i = 0; i < 16; ++i) acc[i] = 0.f;

  for (int k0 = 0; k0 < 64; k0 += 4) {
    float4 w = *(const float4*)&Wt[c][k0];
    #pragma unroll
    for (int i = 0; i < 16; ++i) {
      float4 a = *(const float4*)&At[r0 + i][k0];
      acc[i] += a.x * w.x + a.y * w.y + a.z * w.z + a.w * w.w;
    }
  }

  const float bias = ADD_BIAS ? b[c] : 0.f;
  #pragma unroll
  for (int i = 0; i < 16; ++i) {
    int row = rowBase + r0 + i;
    if (row < N) {
      float v = acc[i] + bias;
      if (RELU_OUT) v = fmaxf(v, 0.f);
      C[row * 64 + c] = v;
    }
  }
}

__global__ __launch_bounds__(256) void init_bias(float* __restrict__ agg,
                                                 const float* __restrict__ b, int n4) {
  int i = blockIdx.x * 256 + threadIdx.x;
  if (i >= n4) return;
  ((float4*)agg)[i] = ((const float4*)b)[i & 15];
}

__global__ __launch_bounds__(256) void scatter_add(const float* __restrict__ h,
                                                   const void* __restrict__ eiPtr,
                                                   const int* __restrict__ flag,
                                                   const float* __restrict__ ew,
                                                   float* __restrict__ agg) {
  int gtid = blockIdx.x * 256 + threadIdx.x;
  int e = gtid >> 6, lane = gtid & 63;
  if (e >= N_EDGES) return;
  int s = load_idx(eiPtr, flag, e);
  int d = load_idx(eiPtr, flag, (long long)N_EDGES + e);
  atomicAdd(&agg[d * 64 + lane], ew[e] * h[s * 64 + lane]);
}

__global__ __launch_bounds__(256) void seg_max(const float* __restrict__ h,
                                               const void* __restrict__ bPtr,
                                               const int* __restrict__ flag,
                                               unsigned* __restrict__ pooled) {
  int gtid = blockIdx.x * 256 + threadIdx.x;
  int n = gtid >> 6, lane = gtid & 63;
  if (n >= N_NODES) return;
  int g = load_idx(bPtr, flag, n);
  atomicMax(&pooled[g * 64 + lane], f2ord(h[n * 64 + lane]));
}

// ---- BatchNorm + linear head ------------------------------------------------

__global__ __launch_bounds__(256) void bn_head(const unsigned* __restrict__ pooled,
                                               const float* __restrict__ gamma,
                                               const float* __restrict__ beta,
                                               const float* __restrict__ linW,
                                               const float* __restrict__ linb,
                                               float* __restrict__ out) {
  __shared__ float P[NGRAPHS][64 + 1];
  __shared__ float mean_s[64], rstd_s[64];
  const int tid = threadIdx.x;

  for (int i = tid; i < NGRAPHS * 64; i += 256) {
    P[i >> 6][i & 63] = ord2f(pooled[i]);
  }
  __syncthreads();

  if (tid < 64) {
    float s = 0.f, ss = 0.f;
    for (int g = 0; g < NGRAPHS; ++g) {
      float v = P[g][tid];
      s += v; ss += v * v;
    }
    float m = s / (float)NGRAPHS;
    float var = ss / (float)NGRAPHS - m * m;
    mean_s[tid] = m;
    rstd_s[tid] = rsqrtf(var + BN_EPS);
  }
  __syncthreads();

  float acc = linb[0];
  #pragma unroll 8
  for (int c = 0; c < 64; ++c) {
    float normed = (P[tid][c] - mean_s[c]) * rstd_s[c] * gamma[c] + beta[c];
    acc += normed * linW[c];
  }
  out[tid] = acc;
}

// ---- launch -----------------------------------------------------------------

extern "C" void kernel_launch(void* const* d_in, const int* in_sizes, int n_in,
                              void* d_out, int out_size, void* d_ws, size_t ws_size,
                              hipStream_t stream) {
  const float* x     = (const float*)d_in[0];
  const void*  ei    = d_in[1];
  const float* ew    = (const float*)d_in[2];
  const void*  batch = d_in[3];
  const float* W1    = (const float*)d_in[4];
  const float* b1    = (const float*)d_in[5];
  const float* W2    = (const float*)d_in[6];
  const float* b2    = (const float*)d_in[7];
  const float* W3    = (const float*)d_in[8];
  const float* b3    = (const float*)d_in[9];
  const float* gamma = (const float*)d_in[10];
  const float* beta  = (const float*)d_in[11];
  const float* linW  = (const float*)d_in[12];
  const float* linb  = (const float*)d_in[13];

  char* ws = (char*)d_ws;
  const size_t MAT  = (size_t)N_NODES * 64 * sizeof(float);           // 25.6 MB
  const size_t TBL  = (size_t)N_NODES * 64 * sizeof(unsigned short);  // 12.8 MB
  const size_t CSRP = (size_t)NBUK * BCAP * sizeof(int2);             // 13.65 MB
  const size_t PTR2 = ((size_t)N_NODES * sizeof(int2) + 255) & ~(size_t)255;

  size_t off = 0;
  unsigned short* uA = (unsigned short*)(ws + off); off += TBL;
  unsigned short* hB = (unsigned short*)(ws + off); off += TBL;
  int2*  csrP   = (int2*)(ws + off);           off += CSRP;
  int2*  tmpP   = (int2*)(ws + off);           off += CSRP;  // separate: gemm1 overlaps place2
  int2*  rowPtr2 = (int2*)(ws + off);          off += PTR2;
  int*   cursor = (int*)(ws + off);            off += 1024;
  unsigned* pooled = (unsigned*)(ws + off);    off += (size_t)NGRAPHS * 64 * sizeof(unsigned);
  int*   flag   = (int*)(ws + off);            off += 256;
  const bool csrPath = (ws_size >= off);

  const int gemmBlocks = (N_NODES + 63) / 64;             // 1563
  const int nodeWaveBlocks = (N_NODES * 64) / 256;        // 25000
  const int poolBlocks = (N_NODES + POOL_RUN * 4 - 1) / (POOL_RUN * 4);  // 3125

  if (csrPath) {
    // ---- build CSR (padded buckets) + overlap layer-1 GEMM with place2 ----
    detect_init<<<1, 256, 0, stream>>>((const unsigned*)ei, flag, cursor, pooled);
    binpass<<<BIN_BLOCKS, 256, 0, stream>>>(ei, flag, ew, cursor, tmpP);
    place2_gemm1<<<NBUK + gemmBlocks, 256, 0, stream>>>(tmpP, cursor, rowPtr2, csrP,
                                                        x, W1, uA);

    // ---- layers: aggregate+bias(+relu) then u = h@W for next layer ----
    pull_relu<<<nodeWaveBlocks, 256, 0, stream>>>(uA, rowPtr2, csrP, b1, hB);
    gemm_u<<<gemmBlocks, 256, 0, stream>>>(hB, W2, uA, N_NODES);
    pull_relu<<<nodeWaveBlocks, 256, 0, stream>>>(uA, rowPtr2, csrP, b2, hB);
    gemm_u<<<gemmBlocks, 256, 0, stream>>>(hB, W3, uA, N_NODES);
    pull_pool<<<poolBlocks, 256, 0, stream>>>(uA, rowPtr2, csrP, b3, batch, flag, pooled);

    bn_head<<<1, 256, 0, stream>>>(pooled, gamma, beta, linW, linb, (float*)d_out);
  } else {
    // ---- fallback: atomic scatter path ----
    float* h   = (float*)ws;
    float* agg = (float*)(ws + MAT);
    unsigned* pooled2 = (unsigned*)(ws + 2 * MAT);
    int* flag2 = (int*)(ws + 2 * MAT + (size_t)NGRAPHS * 64 * sizeof(unsigned));
    detect_i64<<<1, 64, 0, stream>>>((const unsigned*)ei, flag2);
    const int n4 = N_NODES * 16;
    const int initBlocks = (n4 + 255) / 256;
    const int scatBlocks = (N_EDGES * 64) / 256;

    gemm64<false, false, false><<<gemmBlocks, 256, 0, stream>>>(x, W1, b1, h, N_NODES);
    init_bias<<<initBlocks, 256, 0, stream>>>(agg, b1, n4);
    scatter_add<<<scatBlocks, 256, 0, stream>>>(h, ei, flag2, ew, agg);
    gemm64<true, false, false><<<gemmBlocks, 256, 0, stream>>>(agg, W2, b2, h, N_NODES);
    init_bias<<<initBlocks, 256, 0, stream>>>(agg, b2, n4);
    scatter_add<<<scatBlocks, 256, 0, stream>>>(h, ei, flag2, ew, agg);
    gemm64<true, false, false><<<gemmBlocks, 256, 0, stream>>>(agg, W3, b3, h, N_NODES);
    init_bias<<<initBlocks, 256, 0, stream>>>(agg, b3, n4);
    scatter_add<<<scatBlocks, 256, 0, stream>>>(h, ei, flag2, ew, agg);

    hipMemsetAsync(pooled2, 0, (size_t)NGRAPHS * 64 * sizeof(unsigned), stream);
    seg_max<<<nodeWaveBlocks, 256, 0, stream>>>(agg, batch, flag2, pooled2);
    bn_head<<<1, 256, 0, stream>>>(pooled2, gamma, beta, linW, linb, (float*)d_out);
  }
}

// Round 13
// 251.403 us; speedup vs baseline: 9.4934x; 1.1552x over previous
//
#include <hip/hip_runtime.h>

#define N_NODES 100000
#define N_EDGES 1600000
#define NGRAPHS 256
#define BN_EPS 1e-5f
#define NBUK ((N_NODES + 511) >> 9)           // 196 buckets of 512 dst nodes
#define BCAP 8704                             // padded bucket capacity (mean 8163)
#define BIN_EPB 2048                          // edges per binning block
#define BIN_BLOCKS ((N_EDGES + BIN_EPB - 1) / BIN_EPB)  // 782
#define POOL_RUN 8

// ---- helpers ----------------------------------------------------------------

__device__ __forceinline__ unsigned f2ord(float f) {
  unsigned u = __float_as_uint(f);
  return (u & 0x80000000u) ? ~u : (u | 0x80000000u);
}

__device__ __forceinline__ float ord2f(unsigned u) {
  unsigned bits = (u & 0x80000000u) ? (u ^ 0x80000000u) : ~u;
  return __uint_as_float(bits);
}

__device__ __forceinline__ unsigned short f2bf(float f) {   // RNE f32 -> bf16
  unsigned u = __float_as_uint(f);
  unsigned r = u + 0x7FFFu + ((u >> 16) & 1u);
  return (unsigned short)(r >> 16);
}

__device__ __forceinline__ float bf2f(unsigned short b) {
  return __uint_as_float(((unsigned)b) << 16);
}

// Detect int64 vs int32 edge_index + init bucket cursors + zero pooled.
__global__ void detect_init(const unsigned* __restrict__ ei, int* __restrict__ flag,
                            int* __restrict__ cursor, unsigned* __restrict__ pooled) {
  const int tid = threadIdx.x;
  if (tid < NBUK) cursor[tid] = tid * BCAP;
  for (int i = tid; i < NGRAPHS * 64; i += 256) pooled[i] = 0u;  // ordered -inf
  if (tid == 0) {
    int f = 1;
    for (int i = 1; i < 64; i += 2) {
      if (ei[i] != 0u) { f = 0; break; }
    }
    *flag = f;
  }
}

__global__ void detect_i64(const unsigned* __restrict__ ei, int* __restrict__ flag) {
  if (blockIdx.x == 0 && threadIdx.x == 0) {
    int f = 1;
    for (int i = 1; i < 64; i += 2) {
      if (ei[i] != 0u) { f = 0; break; }
    }
    *flag = f;
  }
}

__device__ __forceinline__ int load_idx(const void* p, const int* flag, long long i) {
  return (*flag) ? (int)((const long long*)p)[i] : ((const int*)p)[i];
}

// ---- CSR build: bin edges by dst>>9 into padded bucket slots ----------------
// tmp record: x = src | (localdst<<18), y = weight bits.

__global__ __launch_bounds__(256) void binpass(const void* __restrict__ eiPtr,
                                               const int* __restrict__ flag,
                                               const float* __restrict__ ew,
                                               int* __restrict__ cursor,
                                               int2* __restrict__ tmp) {
  __shared__ int cnt[NBUK];
  __shared__ int base[NBUK];
  const int tid = threadIdx.x;
  const long long chunk0 = (long long)blockIdx.x * BIN_EPB;
  for (int i = tid; i < NBUK; i += 256) cnt[i] = 0;
  __syncthreads();
  int pk[8], wb[8], rk[8], bk[8];
  const bool i64 = (*flag != 0);
  #pragma unroll
  for (int j = 0; j < 8; ++j) {
    long long e = chunk0 + j * 256 + tid;
    rk[j] = -1;
    if (e < N_EDGES) {
      int s, d;
      if (i64) {
        const long long* ei = (const long long*)eiPtr;
        s = (int)ei[e]; d = (int)ei[N_EDGES + e];
      } else {
        const int* ei = (const int*)eiPtr;
        s = ei[e]; d = ei[N_EDGES + e];
      }
      wb[j] = __float_as_int(ew[e]);
      bk[j] = d >> 9;
      pk[j] = s | ((d & 511) << 18);
      rk[j] = atomicAdd(&cnt[bk[j]], 1);
    }
  }
  __syncthreads();
  for (int b = tid; b < NBUK; b += 256) {
    int c = cnt[b];
    base[b] = c ? atomicAdd(&cursor[b], c) : 0;
  }
  __syncthreads();
  #pragma unroll
  for (int j = 0; j < 8; ++j) {
    if (rk[j] >= 0) {
      int pos = base[bk[j]] + rk[j];
      if (pos < (bk[j] + 1) * BCAP) {        // overflow guard (statistically never)
        int2 r; r.x = pk[j]; r.y = wb[j];
        tmp[pos] = r;
      }
    }
  }
}

// ---- merged kernel: blocks [0,NBUK) do place2; rest do layer-1 GEMM ---------
// place2: local hist(512)+LDS scan -> rowPtr2{beg,end}, scatter bucket slice
// into node-sorted csrP (L2-hot window). gemm: uA = x @ W1 (bf16 out).

__global__ __launch_bounds__(256) void place2_gemm1(
    const int2* __restrict__ tmp, const int* __restrict__ cursor,
    int2* __restrict__ rowPtr2, int2* __restrict__ csrP,
    const float* __restrict__ x, const float* __restrict__ W,
    unsigned short* __restrict__ Uout) {
  __shared__ float smem[2][64][68];          // 34.8 KB, unioned
  const int tid = threadIdx.x;

  if (blockIdx.x < NBUK) {
    int* cnt = (int*)&smem[0][0][0];
    int* sc  = cnt + 512;
    int* cur = sc + 256;
    const int b = blockIdx.x;
    const int beg = b * BCAP;
    int cntb = cursor[b] - beg;
    if (cntb > BCAP) cntb = BCAP;
    const int end = beg + cntb;
    cnt[tid] = 0; cnt[tid + 256] = 0;
    __syncthreads();
    for (int i = beg + tid; i < end; i += 256) {
      atomicAdd(&cnt[(tmp[i].x >> 18) & 511], 1);
    }
    __syncthreads();
    int c0 = cnt[2 * tid], c1 = cnt[2 * tid + 1];
    int pairSum = c0 + c1;
    sc[tid] = pairSum;
    __syncthreads();
    for (int off = 1; off < 256; off <<= 1) {
      int t = (tid >= off) ? sc[tid - off] : 0;
      __syncthreads();
      sc[tid] += t;
      __syncthreads();
    }
    int exclPair = sc[tid] - pairSum;
    int base0 = beg + exclPair;
    int base1 = base0 + c0;
    int g0 = (b << 9) + 2 * tid;
    if (g0 < N_NODES)     { int2 r; r.x = base0; r.y = base0 + c0; rowPtr2[g0] = r; }
    if (g0 + 1 < N_NODES) { int2 r; r.x = base1; r.y = base1 + c1; rowPtr2[g0 + 1] = r; }
    cur[2 * tid] = base0;
    cur[2 * tid + 1] = base1;
    __syncthreads();
    for (int i = beg + tid; i < end; i += 256) {
      int2 e = tmp[i];
      int pos = atomicAdd(&cur[(e.x >> 18) & 511], 1);
      int2 r; r.x = e.x & 0x3FFFF; r.y = e.y;
      csrP[pos] = r;
    }
  } else {
    const int rowBase = (blockIdx.x - NBUK) * 64;
    float (*Wt)[68] = (float(*)[68])&smem[0][0][0];   // Wt[c][k]
    float (*At)[68] = (float(*)[68])&smem[1][0][0];
    for (int i = tid; i < 4096; i += 256) {
      int k = i >> 6, c = i & 63;
      Wt[c][k] = W[i];
    }
    const float4* A4 = (const float4*)x;
    #pragma unroll
    for (int j = 0; j < 4; ++j) {
      int t4 = tid + j * 256;
      int g4 = rowBase * 16 + t4;
      float4 v = make_float4(0.f, 0.f, 0.f, 0.f);
      if (g4 < N_NODES * 16) v = A4[g4];
      int r = t4 >> 4, k4 = t4 & 15;
      *(float4*)&At[r][k4 * 4] = v;
    }
    __syncthreads();

    const int c = tid & 63;
    const int r0 = (tid >> 6) * 16;
    float acc[16];
    #pragma unroll
    for (int i = 0; i < 16; ++i) acc[i] = 0.f;
    for (int k0 = 0; k0 < 64; k0 += 4) {
      float4 w = *(const float4*)&Wt[c][k0];
      #pragma unroll
      for (int i = 0; i < 16; ++i) {
        float4 a = *(const float4*)&At[r0 + i][k0];
        acc[i] += a.x * w.x + a.y * w.y + a.z * w.z + a.w * w.w;
      }
    }
    #pragma unroll
    for (int i = 0; i < 16; ++i) {
      int row = rowBase + r0 + i;
      if (row < N_NODES) Uout[(size_t)row * 64 + c] = f2bf(acc[i]);
    }
  }
}

// ---- GEMM: u[N][64](bf16) = A[N][64](bf16) @ W  (layers 2,3) ----------------

__global__ __launch_bounds__(256) void gemm_u(const unsigned short* __restrict__ Ain,
                                              const float* __restrict__ W,
                                              unsigned short* __restrict__ Uout,
                                              int N) {
  __shared__ float Wt[64][68];   // Wt[c][k]
  __shared__ float At[64][68];
  const int tid = threadIdx.x;
  const int rowBase = blockIdx.x * 64;

  for (int i = tid; i < 4096; i += 256) {
    int k = i >> 6, c = i & 63;
    Wt[c][k] = W[i];
  }
  const uint4* A16 = (const uint4*)Ain;
  #pragma unroll
  for (int j = 0; j < 2; ++j) {
    int q = tid + j * 256;
    int r = q >> 3, c8 = (q & 7) * 8;
    int grow = rowBase + r;
    uint4 v = make_uint4(0u, 0u, 0u, 0u);
    if (grow < N) v = A16[(size_t)grow * 8 + (q & 7)];
    float4 f0, f1;
    f0.x = bf2f((unsigned short)(v.x & 0xFFFFu)); f0.y = bf2f((unsigned short)(v.x >> 16));
    f0.z = bf2f((unsigned short)(v.y & 0xFFFFu)); f0.w = bf2f((unsigned short)(v.y >> 16));
    f1.x = bf2f((unsigned short)(v.z & 0xFFFFu)); f1.y = bf2f((unsigned short)(v.z >> 16));
    f1.z = bf2f((unsigned short)(v.w & 0xFFFFu)); f1.w = bf2f((unsigned short)(v.w >> 16));
    *(float4*)&At[r][c8] = f0;
    *(float4*)&At[r][c8 + 4] = f1;
  }
  __syncthreads();

  const int c = tid & 63;
  const int r0 = (tid >> 6) * 16;
  float acc[16];
  #pragma unroll
  for (int i = 0; i < 16; ++i) acc[i] = 0.f;

  for (int k0 = 0; k0 < 64; k0 += 4) {
    float4 w = *(const float4*)&Wt[c][k0];
    #pragma unroll
    for (int i = 0; i < 16; ++i) {
      float4 a = *(const float4*)&At[r0 + i][k0];
      acc[i] += a.x * w.x + a.y * w.y + a.z * w.z + a.w * w.w;
    }
  }

  #pragma unroll
  for (int i = 0; i < 16; ++i) {
    int row = rowBase + r0 + i;
    if (row < N) Uout[(size_t)row * 64 + c] = f2bf(acc[i]);
  }
}

// ---- paired scalar-meta gather (round-10 best): wave = TWO nodes, 8-deep ----

__device__ __forceinline__ float2 gather2(const unsigned short* __restrict__ T,
                                          const int2* __restrict__ csr,
                                          int i0, int e0, int i1, int e1, int lane) {
  float a0 = 0.f, a1 = 0.f, b0 = 0.f, b1 = 0.f;
  // paired main: both nodes have >= 8 edges left
  while ((i0 + 8 <= e0) && (i1 + 8 <= e1)) {
    int2 m0[8], m1[8];
    #pragma unroll
    for (int j = 0; j < 8; ++j) m0[j] = csr[i0 + j];
    #pragma unroll
    for (int j = 0; j < 8; ++j) m1[j] = csr[i1 + j];
    float v0[8], v1[8];
    #pragma unroll
    for (int j = 0; j < 8; ++j) v0[j] = bf2f(T[(size_t)m0[j].x * 64 + lane]);
    #pragma unroll
    for (int j = 0; j < 8; ++j) v1[j] = bf2f(T[(size_t)m1[j].x * 64 + lane]);
    #pragma unroll
    for (int j = 0; j < 8; j += 2) {
      a0 = fmaf(__int_as_float(m0[j].y),     v0[j],     a0);
      a1 = fmaf(__int_as_float(m0[j + 1].y), v0[j + 1], a1);
      b0 = fmaf(__int_as_float(m1[j].y),     v1[j],     b0);
      b1 = fmaf(__int_as_float(m1[j + 1].y), v1[j + 1], b1);
    }
    i0 += 8; i1 += 8;
  }
  // finish node 0 (clamped 8-deep blocks)
  while (i0 < e0) {
    const int last = e0 - 1;
    int2 m[8]; float w[8];
    #pragma unroll
    for (int j = 0; j < 8; ++j) {
      int idx = i0 + j;
      int c = idx < last ? idx : last;
      m[j] = csr[c];
      w[j] = (idx < e0) ? __int_as_float(m[j].y) : 0.f;
    }
    float v[8];
    #pragma unroll
    for (int j = 0; j < 8; ++j) v[j] = bf2f(T[(size_t)m[j].x * 64 + lane]);
    #pragma unroll
    for (int j = 0; j < 8; j += 2) {
      a0 = fmaf(w[j],     v[j],     a0);
      a1 = fmaf(w[j + 1], v[j + 1], a1);
    }
    i0 += 8;
  }
  // finish node 1
  while (i1 < e1) {
    const int last = e1 - 1;
    int2 m[8]; float w[8];
    #pragma unroll
    for (int j = 0; j < 8; ++j) {
      int idx = i1 + j;
      int c = idx < last ? idx : last;
      m[j] = csr[c];
      w[j] = (idx < e1) ? __int_as_float(m[j].y) : 0.f;
    }
    float v[8];
    #pragma unroll
    for (int j = 0; j < 8; ++j) v[j] = bf2f(T[(size_t)m[j].x * 64 + lane]);
    #pragma unroll
    for (int j = 0; j < 8; j += 2) {
      b0 = fmaf(w[j],     v[j],     b0);
      b1 = fmaf(w[j + 1], v[j + 1], b1);
    }
    i1 += 8;
  }
  return make_float2(a0 + a1, b0 + b1);
}

// ---- pull + bias + relu -> bf16 table (2 nodes per wave) --------------------

__global__ __launch_bounds__(256) void pull_relu(const unsigned short* __restrict__ T,
                                                 const int2* __restrict__ rowPtr2,
                                                 const int2* __restrict__ csr,
                                                 const float* __restrict__ bias,
                                                 unsigned short* __restrict__ Hout) {
  int wv = __builtin_amdgcn_readfirstlane((blockIdx.x * 256 + threadIdx.x) >> 6);
  const int lane = threadIdx.x & 63;
  const int n0 = wv * 2;
  if (n0 >= N_NODES) return;
  const bool has1 = (n0 + 1 < N_NODES);
  const int2 be0 = rowPtr2[n0];
  const int2 be1 = has1 ? rowPtr2[n0 + 1] : make_int2(0, 0);
  float2 a = gather2(T, csr, be0.x, be0.y, be1.x, be1.y, lane);
  const float bl = bias[lane];
  Hout[(size_t)n0 * 64 + lane] = f2bf(fmaxf(a.x + bl, 0.f));
  if (has1) Hout[(size_t)(n0 + 1) * 64 + lane] = f2bf(fmaxf(a.y + bl, 0.f));
}

// ---- pull + bias + run-length segment-max pooling (layer 3, paired) ---------

__global__ __launch_bounds__(256) void pull_pool(const unsigned short* __restrict__ T,
                                                 const int2* __restrict__ rowPtr2,
                                                 const int2* __restrict__ csr,
                                                 const float* __restrict__ bias,
                                                 const void* __restrict__ bPtr,
                                                 const int* __restrict__ flag,
                                                 unsigned* __restrict__ pooled) {
  int wseq = __builtin_amdgcn_readfirstlane((blockIdx.x * 256 + threadIdx.x) >> 6);
  const int lane = threadIdx.x & 63;
  const int n0 = wseq * POOL_RUN;
  if (n0 >= N_NODES) return;
  const int n1 = min(n0 + POOL_RUN, N_NODES);
  const float blane = bias[lane];
  int curg = load_idx(bPtr, flag, n0);
  float best = -3.4e38f;
  for (int n = n0; n < n1; n += 2) {
    const bool has1 = (n + 1 < n1);
    const int2 be0 = rowPtr2[n];
    const int2 be1 = has1 ? rowPtr2[n + 1] : make_int2(0, 0);
    float2 vv = gather2(T, csr, be0.x, be0.y, be1.x, be1.y, lane);
    float v0 = vv.x + blane;
    int g0 = load_idx(bPtr, flag, n);
    if (g0 != curg) {
      atomicMax(&pooled[curg * 64 + lane], f2ord(best));
      curg = g0; best = v0;
    } else {
      best = fmaxf(best, v0);
    }
    if (has1) {
      float v1 = vv.y + blane;
      int g1 = load_idx(bPtr, flag, n + 1);
      if (g1 != curg) {
        atomicMax(&pooled[curg * 64 + lane], f2ord(best));
        curg = g1; best = v1;
      } else {
        best = fmaxf(best, v1);
      }
    }
  }
  atomicMax(&pooled[curg * 64 + lane], f2ord(best));
}

// ---- fallback path (small ws): dense GEMM + atomic scatter ------------------

template<bool RELU_IN, bool ADD_BIAS, bool RELU_OUT>
__global__ __launch_bounds__(256) void gemm64(const float* A,
                                              const float* __restrict__ W,
                                              const float* __restrict__ b,
                                              float* C, int N) {
  __shared__ float Wt[64][68];
  __shared__ float At[64][68];
  const int tid = threadIdx.x;
  const int rowBase = blockIdx.x * 64;

  for (int i = tid; i < 4096; i += 256) {
    int k = i >> 6, c = i & 63;
    Wt[c][k] = W[i];
  }
  const float4* A4 = (const float4*)A;
  #pragma unroll
  for (int j = 0; j < 4; ++j) {
    int t4 = tid + j * 256;
    int g4 = rowBase * 16 + t4;
    float4 v = make_float4(0.f, 0.f, 0.f, 0.f);
    if (g4 < N * 16) v = A4[g4];
    if (RELU_IN) {
      v.x = fmaxf(v.x, 0.f); v.y = fmaxf(v.y, 0.f);
      v.z = fmaxf(v.z, 0.f); v.w = fmaxf(v.w, 0.f);
    }
    int r = t4 >> 4, k4 = t4 & 15;
    *(float4*)&At[r][k4 * 4] = v;
  }
  __syncthreads();

  const int c = tid & 63;
  const int r0 = (tid >> 6) * 16;
  float acc[16];
  #pragma unroll
  for (int i = 0; i < 16; ++i) acc[i] = 0.f;

  for (int k0 = 0; k0 < 64; k0 += 4) {
    float4 w = *(const float4*)&Wt[c][k0];
    #pragma unroll
    for (int i = 0; i < 16; ++i) {
      float4 a = *(const float4*)&At[r0 + i][k0];
      acc[i] += a.x * w.x + a.y * w.y + a.z * w.z + a.w * w.w;
    }
  }

  const float bias = ADD_BIAS ? b[c] : 0.f;
  #pragma unroll
  for (int i = 0; i < 16; ++i) {
    int row = rowBase + r0 + i;
    if (row < N) {
      float v = acc[i] + bias;
      if (RELU_OUT) v = fmaxf(v, 0.f);
      C[row * 64 + c] = v;
    }
  }
}

__global__ __launch_bounds__(256) void init_bias(float* __restrict__ agg,
                                                 const float* __restrict__ b, int n4) {
  int i = blockIdx.x * 256 + threadIdx.x;
  if (i >= n4) return;
  ((float4*)agg)[i] = ((const float4*)b)[i & 15];
}

__global__ __launch_bounds__(256) void scatter_add(const float* __restrict__ h,
                                                   const void* __restrict__ eiPtr,
                                                   const int* __restrict__ flag,
                                                   const float* __restrict__ ew,
                                                   float* __restrict__ agg) {
  int gtid = blockIdx.x * 256 + threadIdx.x;
  int e = gtid >> 6, lane = gtid & 63;
  if (e >= N_EDGES) return;
  int s = load_idx(eiPtr, flag, e);
  int d = load_idx(eiPtr, flag, (long long)N_EDGES + e);
  atomicAdd(&agg[d * 64 + lane], ew[e] * h[s * 64 + lane]);
}

__global__ __launch_bounds__(256) void seg_max(const float* __restrict__ h,
                                               const void* __restrict__ bPtr,
                                               const int* __restrict__ flag,
                                               unsigned* __restrict__ pooled) {
  int gtid = blockIdx.x * 256 + threadIdx.x;
  int n = gtid >> 6, lane = gtid & 63;
  if (n >= N_NODES) return;
  int g = load_idx(bPtr, flag, n);
  atomicMax(&pooled[g * 64 + lane], f2ord(h[n * 64 + lane]));
}

// ---- BatchNorm + linear head ------------------------------------------------

__global__ __launch_bounds__(256) void bn_head(const unsigned* __restrict__ pooled,
                                               const float* __restrict__ gamma,
                                               const float* __restrict__ beta,
                                               const float* __restrict__ linW,
                                               const float* __restrict__ linb,
                                               float* __restrict__ out) {
  __shared__ float P[NGRAPHS][64 + 1];
  __shared__ float mean_s[64], rstd_s[64];
  const int tid = threadIdx.x;

  for (int i = tid; i < NGRAPHS * 64; i += 256) {
    P[i >> 6][i & 63] = ord2f(pooled[i]);
  }
  __syncthreads();

  if (tid < 64) {
    float s = 0.f, ss = 0.f;
    for (int g = 0; g < NGRAPHS; ++g) {
      float v = P[g][tid];
      s += v; ss += v * v;
    }
    float m = s / (float)NGRAPHS;
    float var = ss / (float)NGRAPHS - m * m;
    mean_s[tid] = m;
    rstd_s[tid] = rsqrtf(var + BN_EPS);
  }
  __syncthreads();

  float acc = linb[0];
  #pragma unroll 8
  for (int c = 0; c < 64; ++c) {
    float normed = (P[tid][c] - mean_s[c]) * rstd_s[c] * gamma[c] + beta[c];
    acc += normed * linW[c];
  }
  out[tid] = acc;
}

// ---- launch -----------------------------------------------------------------

extern "C" void kernel_launch(void* const* d_in, const int* in_sizes, int n_in,
                              void* d_out, int out_size, void* d_ws, size_t ws_size,
                              hipStream_t stream) {
  const float* x     = (const float*)d_in[0];
  const void*  ei    = d_in[1];
  const float* ew    = (const float*)d_in[2];
  const void*  batch = d_in[3];
  const float* W1    = (const float*)d_in[4];
  const float* b1    = (const float*)d_in[5];
  const float* W2    = (const float*)d_in[6];
  const float* b2    = (const float*)d_in[7];
  const float* W3    = (const float*)d_in[8];
  const float* b3    = (const float*)d_in[9];
  const float* gamma = (const float*)d_in[10];
  const float* beta  = (const float*)d_in[11];
  const float* linW  = (const float*)d_in[12];
  const float* linb  = (const float*)d_in[13];

  char* ws = (char*)d_ws;
  const size_t MAT  = (size_t)N_NODES * 64 * sizeof(float);           // 25.6 MB
  const size_t TBL  = (size_t)N_NODES * 64 * sizeof(unsigned short);  // 12.8 MB
  const size_t CSRP = (size_t)NBUK * BCAP * sizeof(int2);             // 13.65 MB
  const size_t PTR2 = ((size_t)N_NODES * sizeof(int2) + 255) & ~(size_t)255;

  size_t off = 0;
  unsigned short* uA = (unsigned short*)(ws + off); off += TBL;
  unsigned short* hB = (unsigned short*)(ws + off); off += TBL;
  int2*  csrP   = (int2*)(ws + off);           off += CSRP;
  int2*  tmpP   = (int2*)(ws + off);           off += CSRP;  // separate: gemm1 overlaps place2
  int2*  rowPtr2 = (int2*)(ws + off);          off += PTR2;
  int*   cursor = (int*)(ws + off);            off += 1024;
  unsigned* pooled = (unsigned*)(ws + off);    off += (size_t)NGRAPHS * 64 * sizeof(unsigned);
  int*   flag   = (int*)(ws + off);            off += 256;
  const bool csrPath = (ws_size >= off);

  const int gemmBlocks = (N_NODES + 63) / 64;             // 1563
  const int nodeWaveBlocks = (N_NODES * 64) / 256;        // 25000
  const int pairBlocks = (N_NODES / 2 + 3) / 4;           // 12500 (2 nodes/wave)
  const int poolBlocks = (N_NODES + POOL_RUN * 4 - 1) / (POOL_RUN * 4);  // 3125

  if (csrPath) {
    // ---- build CSR (padded buckets) + overlap layer-1 GEMM with place2 ----
    detect_init<<<1, 256, 0, stream>>>((const unsigned*)ei, flag, cursor, pooled);
    binpass<<<BIN_BLOCKS, 256, 0, stream>>>(ei, flag, ew, cursor, tmpP);
    place2_gemm1<<<NBUK + gemmBlocks, 256, 0, stream>>>(tmpP, cursor, rowPtr2, csrP,
                                                        x, W1, uA);

    // ---- layers: aggregate+bias(+relu) then u = h@W for next layer ----
    pull_relu<<<pairBlocks, 256, 0, stream>>>(uA, rowPtr2, csrP, b1, hB);
    gemm_u<<<gemmBlocks, 256, 0, stream>>>(hB, W2, uA, N_NODES);
    pull_relu<<<pairBlocks, 256, 0, stream>>>(uA, rowPtr2, csrP, b2, hB);
    gemm_u<<<gemmBlocks, 256, 0, stream>>>(hB, W3, uA, N_NODES);
    pull_pool<<<poolBlocks, 256, 0, stream>>>(uA, rowPtr2, csrP, b3, batch, flag, pooled);

    bn_head<<<1, 256, 0, stream>>>(pooled, gamma, beta, linW, linb, (float*)d_out);
  } else {
    // ---- fallback: atomic scatter path ----
    float* h   = (float*)ws;
    float* agg = (float*)(ws + MAT);
    unsigned* pooled2 = (unsigned*)(ws + 2 * MAT);
    int* flag2 = (int*)(ws + 2 * MAT + (size_t)NGRAPHS * 64 * sizeof(unsigned));
    detect_i64<<<1, 64, 0, stream>>>((const unsigned*)ei, flag2);
    const int n4 = N_NODES * 16;
    const int initBlocks = (n4 + 255) / 256;
    const int scatBlocks = (N_EDGES * 64) / 256;

    gemm64<false, false, false><<<gemmBlocks, 256, 0, stream>>>(x, W1, b1, h, N_NODES);
    init_bias<<<initBlocks, 256, 0, stream>>>(agg, b1, n4);
    scatter_add<<<scatBlocks, 256, 0, stream>>>(h, ei, flag2, ew, agg);
    gemm64<true, false, false><<<gemmBlocks, 256, 0, stream>>>(agg, W2, b2, h, N_NODES);
    init_bias<<<initBlocks, 256, 0, stream>>>(agg, b2, n4);
    scatter_add<<<scatBlocks, 256, 0, stream>>>(h, ei, flag2, ew, agg);
    gemm64<true, false, false><<<gemmBlocks, 256, 0, stream>>>(agg, W3, b3, h, N_NODES);
    init_bias<<<initBlocks, 256, 0, stream>>>(agg, b3, n4);
    scatter_add<<<scatBlocks, 256, 0, stream>>>(h, ei, flag2, ew, agg);

    hipMemsetAsync(pooled2, 0, (size_t)NGRAPHS * 64 * sizeof(unsigned), stream);
    seg_max<<<nodeWaveBlocks, 256, 0, stream>>>(agg, batch, flag2, pooled2);
    bn_head<<<1, 256, 0, stream>>>(pooled2, gamma, beta, linW, linb, (float*)d_out);
  }
}